// Round 5
// baseline (75.990 us; speedup 1.0000x reference)
//
#include <hip/hip_runtime.h>
#include <hip/hip_bf16.h>
#include <stdint.h>

typedef __attribute__((ext_vector_type(8))) short bf16x8;
typedef __attribute__((ext_vector_type(4))) float f32x4;
typedef __attribute__((ext_vector_type(16))) float f32x16;
typedef __attribute__((ext_vector_type(2))) unsigned int uint32x2;
typedef __attribute__((address_space(3))) void lds_t;
typedef __attribute__((address_space(1))) void glb_t;

#define B_ 4
#define S_ 2048
#define E_ 1024
#define M_ (B_*S_)

static __device__ __forceinline__ ushort f2bf(float f) {
  uint32_t u = __float_as_uint(f);
  u += 0x7fffu + ((u >> 16) & 1u);
  return (ushort)(u >> 16);
}

static __device__ __forceinline__ uint32_t pk_bf16(float lo, float hi) {
  uint32_t r;
  asm("v_cvt_pk_bf16_f32 %0, %1, %2" : "=v"(r) : "v"(lo), "v"(hi));
  return r;
}
static __device__ __forceinline__ float fexp2(float x) {
  float r;
  asm("v_exp_f32 %0, %1" : "=v"(r) : "v"(x));
  return r;
}

// X = [a_lo | b_lo], Y = [a_hi | b_hi]  (lane halves), convention-proof.
static __device__ __forceinline__ void half_zip(uint32_t a, uint32_t b, bool convA,
                                                uint32_t& X, uint32_t& Y) {
  if (convA) {
    uint32x2 r = __builtin_amdgcn_permlane32_swap(b, a, false, false);
    Y = r[0]; X = r[1];
  } else {
    uint32x2 r = __builtin_amdgcn_permlane32_swap(a, b, false, false);
    X = r[0]; Y = r[1];
  }
}

// ---------------- Stage 1: quantum head-attention via MFMA ----------------
// One block per (b,s); wave w owns head-quadrant hi=w (32 heads). Each wave is
// fully self-contained (R3-green dataflow): it generates q into its OWN LDS
// copies (qL for the QK^T operands, qT(+ones rows 8,12) for the PV A-operand),
// no barriers, then 4 S-MFMAs -> exp2 -> permlane zip -> 8 PV-MFMAs into one
// f32x16 acc (rowsum free at reg4 for both lane halves).
__global__ __launch_bounds__(256) void qattn(const float* __restrict__ x,
                                             const float* __restrict__ theta,
                                             ushort* __restrict__ outr) {
  const int wave = threadIdx.x >> 6;
  const int lane = threadIdx.x & 63;
  const int bs = blockIdx.x;
  const int b = bs >> 11, s = bs & 2047;
  const int l31 = lane & 31, hw = lane >> 5;

  __shared__ __align__(16) ushort qL[4][129 * 8];    // per wave: [129][8], row 128 = zeros
  __shared__ __align__(16) ushort qT[4][16 * 144];   // per wave: [16][144], rows 8 & 12 = ones
  ushort* qp = qL[wave];
  ushort* qt = qT[wave];

  // permlane32_swap convention probe (wave-uniform)
  uint32x2 pr = __builtin_amdgcn_permlane32_swap((uint32_t)lane, (uint32_t)(lane + 1000),
                                                 false, false);
  const bool convA = (__builtin_amdgcn_readfirstlane((int)pr[0]) >= 1000);

  float th[8];
  #pragma unroll
  for (int d = 0; d < 8; ++d) th[d] = theta[d];

  const float* xp = x + (size_t)bs * E_ + lane * 16;
  float xr[16];
  #pragma unroll
  for (int i = 0; i < 4; ++i) {
    const float4 v = ((const float4*)xp)[i];
    xr[4*i+0] = v.x; xr[4*i+1] = v.y; xr[4*i+2] = v.z; xr[4*i+3] = v.w;
  }
  float q0[8], q1[8];                       // heads 2*lane, 2*lane+1
  #pragma unroll
  for (int d = 0; d < 8; ++d) {
    q0[d] = __cosf(xr[d] + th[d]);
    q1[d] = __cosf(xr[8 + d] + th[d]);
  }

  // QS^2 = (1/sqrt(8)) * log2(e): folds softmax scale + exp->exp2 into QK operands
  const float QS = 0.71419165f;
  uint32_t qw[8];
  #pragma unroll
  for (int i = 0; i < 4; ++i) {
    qw[i]     = pk_bf16(q0[2*i] * QS, q0[2*i+1] * QS);
    qw[4 + i] = pk_bf16(q1[2*i] * QS, q1[2*i+1] * QS);
  }
  *(uint4*)(qp + (2*lane)     * 8) = *(uint4*)&qw[0];
  *(uint4*)(qp + (2*lane + 1) * 8) = *(uint4*)&qw[4];
  if (lane == 0) *(uint4*)(qp + 128 * 8) = make_uint4(0, 0, 0, 0);

  // qT raw (unscaled): qT[d][g]; rows 8,12 = ones; rows 9-11,13-15 = zeros
  #pragma unroll
  for (int d = 0; d < 8; ++d)
    *(uint32_t*)(qt + d * 144 + 2 * lane) = pk_bf16(q0[d], q1[d]);
  *(uint32_t*)(qt + 8 * 144 + 2 * lane) = 0x3F803F80u;
  #pragma unroll
  for (int r = 9; r < 16; ++r)
    *(uint32_t*)(qt + r * 144 + 2 * lane) = (r == 12) ? 0x3F803F80u : 0u;

  // PV A-frags: A[m=d][k=g]; rows 16..31 zero
  bf16x8 qtf[8];
  const bf16x8 zf = {};
  #pragma unroll
  for (int ks = 0; ks < 8; ++ks) {
    bf16x8 f = *(const bf16x8*)(qt + (l31 & 15) * 144 + ks * 16 + hw * 8);
    qtf[ks] = (l31 < 16) ? f : zf;
  }

  const int hi = wave;
  const int brow = (lane < 32) ? (hi * 32 + l31) : 128;
  const bf16x8 bq = *(const bf16x8*)(qp + brow * 8);

  f32x16 oacc = {};   // O^T: col h = hi*32+l31, row d=(reg&3)+8*(reg>>2)+4*hw

  #pragma unroll
  for (int gj = 0; gj < 4; ++gj) {
    const int arow = (lane < 32) ? (gj * 32 + l31) : 128;
    const bf16x8 aq = *(const bf16x8*)(qp + arow * 8);
    f32x16 sc = {};
    sc = __builtin_amdgcn_mfma_f32_32x32x16_bf16(aq, bq, sc, 0, 0, 0);
    float p[16];
    #pragma unroll
    for (int i = 0; i < 16; ++i) p[i] = fexp2(sc[i]);
    #pragma unroll
    for (int sl = 0; sl < 2; ++sl) {
      const int pb = sl * 8;
      const uint32_t u = pk_bf16(p[pb+0], p[pb+1]);
      const uint32_t v = pk_bf16(p[pb+2], p[pb+3]);
      const uint32_t w = pk_bf16(p[pb+4], p[pb+5]);
      const uint32_t z = pk_bf16(p[pb+6], p[pb+7]);
      uint32_t f0, f1, f2, f3;
      half_zip(u, w, convA, f0, f2);
      half_zip(v, z, convA, f1, f3);
      uint32_t fr[4] = {f0, f1, f2, f3};
      oacc = __builtin_amdgcn_mfma_f32_32x32x16_bf16(qtf[gj*2 + sl], *(const bf16x8*)fr,
                                                     oacc, 0, 0, 0);
    }
  }

  // epilogue: regs0-3 = d 0-3 (hw=0) / d 4-7 (hw=1); reg4 = rowsum for BOTH halves
  const int scol = s & 127, srow = s >> 7;
  const float inv = __builtin_amdgcn_rcpf(oacc[4]);
  const uint32_t o01 = pk_bf16(oacc[0] * inv, oacc[1] * inv);
  const uint32_t o23 = pk_bf16(oacc[2] * inv, oacc[3] * inv);
  const int h = hi * 32 + l31;
  const size_t row = (size_t)(b * 2048 + h * 16 + srow);
  *(uint2*)(outr + row * E_ + scol * 8 + hw * 4) = make_uint2(o01, o23);
}

// ---------------- W (f32) -> bf16 ----------------
__global__ __launch_bounds__(256) void wconv(const float* __restrict__ W,
                                             ushort* __restrict__ Wb) {
  const int i = blockIdx.x * 256 + threadIdx.x;
  const float4 v = ((const float4*)W)[i];
  ushort4 o;
  o.x = f2bf(v.x); o.y = f2bf(v.y); o.z = f2bf(v.z); o.w = f2bf(v.w);
  ((ushort4*)Wb)[i] = o;
}

// ---------------- Stage 2: C[m,n] = sum_k A[m,k]*W[n,k] + bias[n] ----------------
__global__ __launch_bounds__(256) void gemm_bt(const ushort* __restrict__ A,
                                               const ushort* __restrict__ Bw,
                                               const float* __restrict__ bias,
                                               float* __restrict__ C) {
  __shared__ __align__(16) ushort As[128 * 32];
  __shared__ __align__(16) ushort Bs[128 * 32];

  const int t = threadIdx.x;
  const int lane = t & 63;
  const int wavei = t >> 6;
  const int wr = wavei >> 1, wc = wavei & 1;
  const int lhi = lane >> 4, llo = lane & 15;
  const size_t ar0 = (size_t)blockIdx.x * 128;
  const size_t br0 = (size_t)blockIdx.y * 128;

  const int c0 = t, c1 = t + 256;
  const int r0 = c0 >> 2, kp0 = (c0 & 3) * 8;
  const int r1 = c1 >> 2, kp1 = (c1 & 3) * 8;

  f32x4 acc[4][4] = {};

  for (int k0 = 0; k0 < E_; k0 += 32) {
    __builtin_amdgcn_global_load_lds((const glb_t*)(A  + (ar0 + r0) * E_ + k0 + kp0),
                                     (lds_t*)(As + c0 * 8), 16, 0, 0);
    __builtin_amdgcn_global_load_lds((const glb_t*)(A  + (ar0 + r1) * E_ + k0 + kp1),
                                     (lds_t*)(As + c1 * 8), 16, 0, 0);
    __builtin_amdgcn_global_load_lds((const glb_t*)(Bw + (br0 + r0) * E_ + k0 + kp0),
                                     (lds_t*)(Bs + c0 * 8), 16, 0, 0);
    __builtin_amdgcn_global_load_lds((const glb_t*)(Bw + (br0 + r1) * E_ + k0 + kp1),
                                     (lds_t*)(Bs + c1 * 8), 16, 0, 0);
    __syncthreads();

    bf16x8 af[4], bfr[4];
    #pragma unroll
    for (int i = 0; i < 4; ++i)
      af[i] = *(const bf16x8*)(As + (wr * 64 + i * 16 + llo) * 32 + lhi * 8);
    #pragma unroll
    for (int j = 0; j < 4; ++j)
      bfr[j] = *(const bf16x8*)(Bs + (wc * 64 + j * 16 + llo) * 32 + lhi * 8);

    #pragma unroll
    for (int i = 0; i < 4; ++i)
      #pragma unroll
      for (int j = 0; j < 4; ++j)
        acc[i][j] = __builtin_amdgcn_mfma_f32_16x16x32_bf16(af[i], bfr[j], acc[i][j], 0, 0, 0);

    __syncthreads();
  }

  #pragma unroll
  for (int j = 0; j < 4; ++j) {
    const int n = (int)br0 + wc * 64 + j * 16 + llo;
    const float bj = bias[n];
    #pragma unroll
    for (int i = 0; i < 4; ++i) {
      const int mb = (int)ar0 + wr * 64 + i * 16 + lhi * 4;
      #pragma unroll
      for (int r = 0; r < 4; ++r) {
        C[(size_t)(mb + r) * E_ + n] = acc[i][j][r] + bj;
      }
    }
  }
}

extern "C" void kernel_launch(void* const* d_in, const int* in_sizes, int n_in,
                              void* d_out, int out_size, void* d_ws, size_t ws_size,
                              hipStream_t stream) {
  const float* x     = (const float*)d_in[0];
  const float* theta = (const float*)d_in[1];
  const float* W     = (const float*)d_in[2];
  const float* bias  = (const float*)d_in[3];
  float* out = (float*)d_out;

  ushort* outr = (ushort*)d_ws;
  ushort* Wb   = (ushort*)((char*)d_ws + (size_t)M_ * E_ * 2);

  qattn<<<M_, 256, 0, stream>>>(x, theta, outr);
  wconv<<<(E_ * E_) / (256 * 4), 256, 0, stream>>>(W, Wb);
  dim3 g(M_ / 128, E_ / 128);
  gemm_bt<<<g, 256, 0, stream>>>(outr, Wb, bias, out);
}

// Round 6
// 69.273 us; speedup vs baseline: 1.0970x; 1.0970x over previous
//
#include <hip/hip_runtime.h>
#include <hip/hip_bf16.h>
#include <stdint.h>

typedef __attribute__((ext_vector_type(8))) short bf16x8;
typedef __attribute__((ext_vector_type(4))) float f32x4;
typedef __attribute__((ext_vector_type(16))) float f32x16;
typedef __attribute__((ext_vector_type(2))) unsigned int uint32x2;
typedef __attribute__((address_space(3))) void lds_t;
typedef __attribute__((address_space(1))) void glb_t;

#define B_ 4
#define S_ 2048
#define E_ 1024
#define M_ (B_*S_)

static __device__ __forceinline__ ushort f2bf(float f) {
  uint32_t u = __float_as_uint(f);
  u += 0x7fffu + ((u >> 16) & 1u);
  return (ushort)(u >> 16);
}

static __device__ __forceinline__ uint32_t pk_bf16(float lo, float hi) {
  uint32_t r;
  asm("v_cvt_pk_bf16_f32 %0, %1, %2" : "=v"(r) : "v"(lo), "v"(hi));
  return r;
}
static __device__ __forceinline__ float fexp2(float x) {
  float r;
  asm("v_exp_f32 %0, %1" : "=v"(r) : "v"(x));
  return r;
}

// X = [a_lo | b_lo], Y = [a_hi | b_hi]  (lane halves), convention-proof.
static __device__ __forceinline__ void half_zip(uint32_t a, uint32_t b, bool convA,
                                                uint32_t& X, uint32_t& Y) {
  if (convA) {
    uint32x2 r = __builtin_amdgcn_permlane32_swap(b, a, false, false);
    Y = r[0]; X = r[1];
  } else {
    uint32x2 r = __builtin_amdgcn_permlane32_swap(a, b, false, false);
    X = r[0]; Y = r[1];
  }
}

// ---------------- Stage 1: quantum head-attention via MFMA ----------------
// One block per (b,s); COOPERATIVE generation: wave w generates heads
// [32w, 32w+32) into shared qp/qt (every wave is an LDS writer -> no
// "no-writes-on-this-path" hoisting hazard), one barrier (+sched_barrier),
// then wave w consumes quadrant hi=w with the R5-green dataflow:
// 4 S-MFMAs -> exp2 -> permlane zip -> 8 PV-MFMAs into one f32x16 acc
// (rowsum free at reg4 for both lane halves via ones rows 8 & 12).
__global__ __launch_bounds__(256) void qattn(const float* __restrict__ x,
                                             const float* __restrict__ theta,
                                             ushort* __restrict__ outr) {
  const int wave = threadIdx.x >> 6;
  const int lane = threadIdx.x & 63;
  // XCD-aware swizzle: consecutive-in-time blocks on one XCD get consecutive s
  const int bid = blockIdx.x;
  const int bs = (bid & 7) * 1024 + (bid >> 3);
  const int b = bs >> 11, s = bs & 2047;
  const int l31 = lane & 31, hw = lane >> 5;

  __shared__ __align__(16) ushort qp[129 * 8];    // [129][8] scaled q, row 128 = zeros
  __shared__ __align__(16) ushort qt[16 * 144];   // [16][144] raw q^T, rows 8 & 12 = ones

  // permlane32_swap convention probe (wave-uniform)
  uint32x2 pr = __builtin_amdgcn_permlane32_swap((uint32_t)lane, (uint32_t)(lane + 1000),
                                                 false, false);
  const bool convA = (__builtin_amdgcn_readfirstlane((int)pr[0]) >= 1000);

  // ---- cooperative generation: lane covers head h = 32*wave + (lane>>1),
  //      d-half dh = (lane&1)*4 ----
  {
    const int h  = 32 * wave + (lane >> 1);
    const int dh = (lane & 1) * 4;
    const float4 xv = *(const float4*)(x + (size_t)bs * E_ + h * 8 + dh);
    float q[4];
    q[0] = __cosf(xv.x + theta[dh + 0]);
    q[1] = __cosf(xv.y + theta[dh + 1]);
    q[2] = __cosf(xv.z + theta[dh + 2]);
    q[3] = __cosf(xv.w + theta[dh + 3]);

    // QS^2 = (1/sqrt(8)) * log2(e): folds softmax scale + exp->exp2 into QK operands
    const float QS = 0.71419165f;
    uint2 pw;
    pw.x = pk_bf16(q[0] * QS, q[1] * QS);
    pw.y = pk_bf16(q[2] * QS, q[3] * QS);
    *(uint2*)(qp + h * 8 + dh) = pw;                       // scaled, for QK^T operands

    #pragma unroll
    for (int j = 0; j < 4; ++j)                            // raw, for PV A-operand
      qt[(dh + j) * 144 + h] = f2bf(q[j]);
    #pragma unroll
    for (int j = 0; j < 4; ++j)                            // rows 8..15: ones at 8,12
      qt[(8 + dh + j) * 144 + h] = (j == 0) ? (ushort)0x3F80u : (ushort)0u;

    if (lane == 0) *(uint4*)(qp + 128 * 8) = make_uint4(0, 0, 0, 0);  // K-pad row
  }
  __syncthreads();
  __builtin_amdgcn_sched_barrier(0);

  // ---- consumption (identical to R5-green dataflow) ----
  bf16x8 qtf[8];
  const bf16x8 zf = {};
  #pragma unroll
  for (int ks = 0; ks < 8; ++ks) {
    bf16x8 f = *(const bf16x8*)(qt + (l31 & 15) * 144 + ks * 16 + hw * 8);
    qtf[ks] = (l31 < 16) ? f : zf;
  }

  const int hi = wave;
  const int brow = (lane < 32) ? (hi * 32 + l31) : 128;
  const bf16x8 bq = *(const bf16x8*)(qp + brow * 8);

  f32x16 oacc = {};   // O^T: col h = hi*32+l31, row d=(reg&3)+8*(reg>>2)+4*hw

  #pragma unroll
  for (int gj = 0; gj < 4; ++gj) {
    const int arow = (lane < 32) ? (gj * 32 + l31) : 128;
    const bf16x8 aq = *(const bf16x8*)(qp + arow * 8);
    f32x16 sc = {};
    sc = __builtin_amdgcn_mfma_f32_32x32x16_bf16(aq, bq, sc, 0, 0, 0);
    float p[16];
    #pragma unroll
    for (int i = 0; i < 16; ++i) p[i] = fexp2(sc[i]);
    #pragma unroll
    for (int sl = 0; sl < 2; ++sl) {
      const int pb = sl * 8;
      const uint32_t u = pk_bf16(p[pb+0], p[pb+1]);
      const uint32_t v = pk_bf16(p[pb+2], p[pb+3]);
      const uint32_t w = pk_bf16(p[pb+4], p[pb+5]);
      const uint32_t z = pk_bf16(p[pb+6], p[pb+7]);
      uint32_t f0, f1, f2, f3;
      half_zip(u, w, convA, f0, f2);
      half_zip(v, z, convA, f1, f3);
      uint32_t fr[4] = {f0, f1, f2, f3};
      oacc = __builtin_amdgcn_mfma_f32_32x32x16_bf16(qtf[gj*2 + sl], *(const bf16x8*)fr,
                                                     oacc, 0, 0, 0);
    }
  }

  // epilogue: regs0-3 = d 0-3 (hw=0) / d 4-7 (hw=1); reg4 = rowsum for BOTH halves
  const int scol = s & 127, srow = s >> 7;
  const float inv = __builtin_amdgcn_rcpf(oacc[4]);
  const uint32_t o01 = pk_bf16(oacc[0] * inv, oacc[1] * inv);
  const uint32_t o23 = pk_bf16(oacc[2] * inv, oacc[3] * inv);
  const int h = hi * 32 + l31;
  const size_t row = (size_t)(b * 2048 + h * 16 + srow);
  *(uint2*)(outr + row * E_ + scol * 8 + hw * 4) = make_uint2(o01, o23);
}

// ---------------- W (f32) -> bf16 ----------------
__global__ __launch_bounds__(256) void wconv(const float* __restrict__ W,
                                             ushort* __restrict__ Wb) {
  const int i = blockIdx.x * 256 + threadIdx.x;
  const float4 v = ((const float4*)W)[i];
  ushort4 o;
  o.x = f2bf(v.x); o.y = f2bf(v.y); o.z = f2bf(v.z); o.w = f2bf(v.w);
  ((ushort4*)Wb)[i] = o;
}

// ---------------- Stage 2: C[m,n] = sum_k A[m,k]*W[n,k] + bias[n] ----------------
__global__ __launch_bounds__(256) void gemm_bt(const ushort* __restrict__ A,
                                               const ushort* __restrict__ Bw,
                                               const float* __restrict__ bias,
                                               float* __restrict__ C) {
  __shared__ __align__(16) ushort As[128 * 32];
  __shared__ __align__(16) ushort Bs[128 * 32];

  const int t = threadIdx.x;
  const int lane = t & 63;
  const int wavei = t >> 6;
  const int wr = wavei >> 1, wc = wavei & 1;
  const int lhi = lane >> 4, llo = lane & 15;
  const size_t ar0 = (size_t)blockIdx.x * 128;
  const size_t br0 = (size_t)blockIdx.y * 128;

  const int c0 = t, c1 = t + 256;
  const int r0 = c0 >> 2, kp0 = (c0 & 3) * 8;
  const int r1 = c1 >> 2, kp1 = (c1 & 3) * 8;

  f32x4 acc[4][4] = {};

  for (int k0 = 0; k0 < E_; k0 += 32) {
    __builtin_amdgcn_global_load_lds((const glb_t*)(A  + (ar0 + r0) * E_ + k0 + kp0),
                                     (lds_t*)(As + c0 * 8), 16, 0, 0);
    __builtin_amdgcn_global_load_lds((const glb_t*)(A  + (ar0 + r1) * E_ + k0 + kp1),
                                     (lds_t*)(As + c1 * 8), 16, 0, 0);
    __builtin_amdgcn_global_load_lds((const glb_t*)(Bw + (br0 + r0) * E_ + k0 + kp0),
                                     (lds_t*)(Bs + c0 * 8), 16, 0, 0);
    __builtin_amdgcn_global_load_lds((const glb_t*)(Bw + (br0 + r1) * E_ + k0 + kp1),
                                     (lds_t*)(Bs + c1 * 8), 16, 0, 0);
    __syncthreads();

    bf16x8 af[4], bfr[4];
    #pragma unroll
    for (int i = 0; i < 4; ++i)
      af[i] = *(const bf16x8*)(As + (wr * 64 + i * 16 + llo) * 32 + lhi * 8);
    #pragma unroll
    for (int j = 0; j < 4; ++j)
      bfr[j] = *(const bf16x8*)(Bs + (wc * 64 + j * 16 + llo) * 32 + lhi * 8);

    #pragma unroll
    for (int i = 0; i < 4; ++i)
      #pragma unroll
      for (int j = 0; j < 4; ++j)
        acc[i][j] = __builtin_amdgcn_mfma_f32_16x16x32_bf16(af[i], bfr[j], acc[i][j], 0, 0, 0);

    __syncthreads();
  }

  #pragma unroll
  for (int j = 0; j < 4; ++j) {
    const int n = (int)br0 + wc * 64 + j * 16 + llo;
    const float bj = bias[n];
    #pragma unroll
    for (int i = 0; i < 4; ++i) {
      const int mb = (int)ar0 + wr * 64 + i * 16 + lhi * 4;
      #pragma unroll
      for (int r = 0; r < 4; ++r) {
        C[(size_t)(mb + r) * E_ + n] = acc[i][j][r] + bj;
      }
    }
  }
}

extern "C" void kernel_launch(void* const* d_in, const int* in_sizes, int n_in,
                              void* d_out, int out_size, void* d_ws, size_t ws_size,
                              hipStream_t stream) {
  const float* x     = (const float*)d_in[0];
  const float* theta = (const float*)d_in[1];
  const float* W     = (const float*)d_in[2];
  const float* bias  = (const float*)d_in[3];
  float* out = (float*)d_out;

  ushort* outr = (ushort*)d_ws;
  ushort* Wb   = (ushort*)((char*)d_ws + (size_t)M_ * E_ * 2);

  qattn<<<M_, 256, 0, stream>>>(x, theta, outr);
  wconv<<<(E_ * E_) / (256 * 4), 256, 0, stream>>>(W, Wb);
  dim3 g(M_ / 128, E_ / 128);
  gemm_bt<<<g, 256, 0, stream>>>(outr, Wb, bias, out);
}